// Round 14
// baseline (212.469 us; speedup 1.0000x reference)
//
#include <hip/hip_runtime.h>

#define T_NUM   100000
#define W_NUM   500
#define N_NODES 100500
#define A_NUM   1000000
#define FEAT    512
#define HID     128
#define CLS     10

#define CSR_STRIDE  40       // per-task worker slots; Poisson(10) tail @40 ~ 3e-16
#define CSRT_STRIDE 2432     // per-worker task slots; Binomial(1M,1/500) 9-sigma
#define BM          64       // GEMM rows per block (4 waves x 16 rows)
#define HPAD        136      // Hs row stride (bf16 elems)
#define NRANGE      8        // XCDs
#define TRNG        (T_NUM / NRANGE)   // 12500 tasks per XCD range
#define WRNG        64       // workers per XCD range (last: 52)
#define CHUNK       2048
#define NCHUNK      ((A_NUM + CHUNK - 1) / CHUNK)   // 489
#define BLD_CAP     64       // per-(block,worker) LDS slots
#define GEMM_BLKS   ((T_NUM + BM - 1) / BM)          // 1563
#define BUILD_BLKS  1024

typedef short bf16x8 __attribute__((ext_vector_type(8)));
typedef float f32x4  __attribute__((ext_vector_type(4)));

__device__ __forceinline__ unsigned cvtpk(float lo, float hi) {
    unsigned r;
    asm("v_cvt_pk_bf16_f32 %0, %1, %2" : "=v"(r) : "v"(lo), "v"(hi));
    return r;
}
__device__ __forceinline__ unsigned short f2bf1(float x) {
    return (unsigned short)cvtpk(x, x);
}

// ---------------- K1: weight preps only (Wt transpose + B2t) ----------
__global__ void k_prepw(const float* __restrict__ W, unsigned short* __restrict__ Wt,
                        unsigned short* __restrict__ B2t,
                        const float* __restrict__ Wm, const float* __restrict__ Wl) {
    int bid = blockIdx.x;
    if (bid < HID) {
        int c = bid;
        for (int k = threadIdx.x; k < FEAT; k += blockDim.x)
            Wt[(size_t)c * FEAT + k] = f2bf1(W[(size_t)k * HID + c]);
    } else {
        for (int i = threadIdx.x; i < 32 * HID; i += blockDim.x) {
            int c = i / HID, k = i % HID;
            float v = 0.f;
            if (c < 10)                 v = Wm[k * CLS + c];
            else if (c >= 16 && c < 26) v = Wl[k * CLS + (c - 16)];
            B2t[i] = f2bf1(v);
        }
    }
}

// ---------------- K2: FUSED  (blocks<GEMM_BLKS: GEMM | else: CSR build) ---
// GEMM path writes UNSCALED projections to g (dinv applied by consumers),
// removing the cnt dependency so build+gemm can overlap spatially.
__global__ __launch_bounds__(256, 7) void k_fused(
        const float* __restrict__ A, const unsigned short* __restrict__ Wt,
        const float* __restrict__ bias, const unsigned short* __restrict__ B2t,
        float* __restrict__ g,
        const int* __restrict__ answers, int* __restrict__ cnt,
        int* __restrict__ wcur, int* __restrict__ tick,
        unsigned short* __restrict__ csrW, int* __restrict__ csrT) {
    __shared__ __align__(16) char smem[17664];
    const int tid = threadIdx.x;

    if (blockIdx.x >= GEMM_BLKS) {
        // ================= BUILD path (XCD-pinned + NT loads + steal) ====
        int* lcnt    = (int*)smem;              // [64]
        int* llist   = (int*)(smem + 256);      // [64*64]
        int* s_chunk = (int*)(smem + 16640);

        int xcc;
        asm volatile("s_getreg_b32 %0, hwreg(HW_REG_XCC_ID)" : "=s"(xcc));
        const int r0 = xcc & (NRANGE - 1);

        for (int rr = 0; rr < NRANGE; rr++) {
            const int re  = (r0 + rr) & (NRANGE - 1);
            const int tlo = re * TRNG, thi = tlo + TRNG;
            const int wlo = re * WRNG;

            for (int i = tid; i < WRNG; i += 256) lcnt[i] = 0;

            for (;;) {
                __syncthreads();
                if (tid == 0) *s_chunk = atomicAdd(&tick[re * 16], 1);
                __syncthreads();
                const int c = *s_chunk;
                if (c >= NCHUNK) break;
                const int base = c * CHUNK;
                const int end  = (base + CHUNK < A_NUM) ? base + CHUNK : A_NUM;
                for (int a = base + tid; a < end; a += 256) {
                    int t = __builtin_nontemporal_load(answers + a * 3);
                    int w = __builtin_nontemporal_load(answers + a * 3 + 1);
                    if (t >= tlo && t < thi) {
                        int p = atomicAdd(&cnt[t], 1);
                        if (p < CSR_STRIDE)
                            csrW[(size_t)t * CSR_STRIDE + p] = (unsigned short)w;
                    }
                    int wr = w - wlo;
                    if (wr >= 0 && wr < WRNG && w < W_NUM) {
                        int s = atomicAdd(&lcnt[wr], 1);
                        if (s < BLD_CAP) llist[wr * BLD_CAP + s] = t;
                        else {                               // overflow fallback
                            int q = atomicAdd(&wcur[w * 16], 1);
                            if (q < CSRT_STRIDE)
                                csrT[(size_t)w * CSRT_STRIDE + q] = t;
                        }
                    }
                }
            }
            // flush this range's LDS lists (all atomics preceded last barrier)
            for (int wr = tid; wr < WRNG; wr += 256) {
                int w = wlo + wr;
                if (w >= W_NUM) continue;
                int c = lcnt[wr];
                if (c > BLD_CAP) c = BLD_CAP;
                if (c == 0) continue;
                int qb = atomicAdd(&wcur[w * 16], c);
                int* dst = csrT + (size_t)w * CSRT_STRIDE;
                for (int j = 0; j < c; j++) {
                    int q = qb + j;
                    if (q < CSRT_STRIDE) dst[q] = llist[wr * BLD_CAP + j];
                }
            }
            __syncthreads();   // flush reads done before next range resets LDS
        }
        return;
    }

    // ================= GEMM path ========================================
    const int lane = tid & 63;
    const int wv   = tid >> 6;
    const int l15  = lane & 15;
    const int lkg  = lane >> 4;
    const int row  = blockIdx.x * BM + wv * 16 + l15;
    const int rowc = row < T_NUM ? row : T_NUM - 1;
    const float* aptr = A + (size_t)rowc * FEAT + lkg * 8;

    const int scol  = tid >> 1;
    const int shalf = tid & 1;
    const int sswz  = (scol & 7) << 4;
    const int sb0   = (scol * 64 + shalf * 32) ^ sswz;
    const int sb1   = (scol * 64 + shalf * 32 + 16) ^ sswz;
    const unsigned short* sptr = Wt + (size_t)scol * FEAT + shalf * 16;

    const int rswz = (l15 & 7) << 4;

    f32x4 acc[8];
    #pragma unroll
    for (int nt = 0; nt < 8; nt++) acc[nt] = (f32x4){0.f, 0.f, 0.f, 0.f};

    union LU { int4 i; bf16x8 h; };
    union PK { unsigned u[4]; bf16x8 h; };

    float4 ca0 = *(const float4*)(aptr);
    float4 ca1 = *(const float4*)(aptr + 4);
    *(int4*)(smem + sb0) = *(const int4*)(sptr);
    *(int4*)(smem + sb1) = *(const int4*)(sptr + 8);
    __syncthreads();

    for (int ks = 0; ks < 16; ks++) {
        const int k0 = ks * 32;
        float4 na0, na1;
        if (ks < 15) {
            na0 = *(const float4*)(aptr + k0 + 32);
            na1 = *(const float4*)(aptr + k0 + 36);
            char* nb = smem + (((ks + 1) & 1) << 13);
            *(int4*)(nb + sb0) = *(const int4*)(sptr + k0 + 32);
            *(int4*)(nb + sb1) = *(const int4*)(sptr + k0 + 40);
        }
        PK pk;
        pk.u[0] = cvtpk(ca0.x, ca0.y);
        pk.u[1] = cvtpk(ca0.z, ca0.w);
        pk.u[2] = cvtpk(ca1.x, ca1.y);
        pk.u[3] = cvtpk(ca1.z, ca1.w);
        const char* bb = smem + ((ks & 1) << 13);
        #pragma unroll
        for (int nt = 0; nt < 8; nt++) {
            const int boff = ((nt * 16 + l15) * 64 + lkg * 16) ^ rswz;
            LU bu; bu.i = *(const int4*)(bb + boff);
            acc[nt] = __builtin_amdgcn_mfma_f32_16x16x32_bf16(pk.h, bu.h, acc[nt], 0, 0, 0);
        }
        ca0 = na0; ca1 = na1;
        __syncthreads();
    }

    unsigned short* hw = (unsigned short*)smem + wv * 16 * HPAD;
    #pragma unroll
    for (int nt = 0; nt < 8; nt++) {
        float bv = bias[nt * 16 + l15];
        #pragma unroll
        for (int r = 0; r < 4; r++) {
            float h = fmaxf(acc[nt][r] + bv, 0.f);
            hw[(lkg * 4 + r) * HPAD + nt * 16 + l15] = f2bf1(h);
        }
    }

    f32x4 acc2[2];
    acc2[0] = (f32x4){0.f, 0.f, 0.f, 0.f};
    acc2[1] = (f32x4){0.f, 0.f, 0.f, 0.f};
    #pragma unroll
    for (int s = 0; s < 4; s++) {
        LU a2;
        a2.i = *(const int4*)(hw + l15 * HPAD + s * 32 + lkg * 8);
        #pragma unroll
        for (int j = 0; j < 2; j++) {
            LU b2;
            b2.i = *(const int4*)(B2t + (size_t)(j * 16 + l15) * HID + s * 32 + lkg * 8);
            acc2[j] = __builtin_amdgcn_mfma_f32_16x16x32_bf16(a2.h, b2.h, acc2[j], 0, 0, 0);
        }
    }

    // write RAW projections (dinv applied by consumers)
    if (l15 < 10) {
        #pragma unroll
        for (int r = 0; r < 4; r++) {
            int node = blockIdx.x * BM + wv * 16 + lkg * 4 + r;
            if (node < T_NUM) {
                g[(size_t)node * 20 + l15]      = acc2[0][r];
                g[(size_t)node * 20 + 10 + l15] = acc2[1][r];
            }
        }
    }
}

// ---------------- K3: worker projections (needs final wcur) ----------
__global__ void k_wproj(const float* __restrict__ WF,
                        const float* __restrict__ Wm, const float* __restrict__ Wl,
                        const int* __restrict__ wcur, float* __restrict__ g) {
    int idx = blockIdx.x * blockDim.x + threadIdx.x;
    if (idx >= W_NUM * 20) return;
    int w = idx / 20, oc = idx % 20;
    const float* Wc = (oc < 10) ? (Wm + oc) : (Wl + (oc - 10));
    const float* x  = WF + (size_t)w * HID;
    float s = 0.f;
    #pragma unroll 8
    for (int k = 0; k < HID; k++) s = fmaf(x[k], Wc[k * CLS], s);
    float gi = rsqrtf((float)(wcur[w * 16] + 1)) * s;   // scaled (dinv_w * proj)
    g[(size_t)(T_NUM + w) * 20 + oc] = gi;
}

// ---------------- K4: worker accumulation (per-edge dinv) + finalize ------
__global__ __launch_bounds__(256) void k_wacc(
        const int* __restrict__ csrT, const int* __restrict__ wcur,
        const int* __restrict__ cnt, const float* __restrict__ g,
        const float* __restrict__ b_mean, const float* __restrict__ b_ls,
        const float* __restrict__ eps,
        float* __restrict__ out_mean, float* __restrict__ out_ls,
        float* __restrict__ z) {
    const int w    = blockIdx.x;
    const int tid  = threadIdx.x;
    const int lane = tid & 63;
    const int wv   = tid >> 6;

    int len = wcur[w * 16];
    int lim = len < CSRT_STRIDE ? len : CSRT_STRIDE;
    const int* lst = csrT + (size_t)w * CSRT_STRIDE;

    float a[20];
    #pragma unroll
    for (int c = 0; c < 20; c++) a[c] = 0.f;

    for (int e = tid; e < lim; e += 256) {
        int t = lst[e];
        float dit = rsqrtf((float)(cnt[t] + 1));     // g[t] is raw -> scale here
        const float4* gr = (const float4*)(g + (size_t)t * 20);
        float4 v0 = gr[0], v1 = gr[1], v2 = gr[2], v3 = gr[3], v4 = gr[4];
        a[0] += dit * v0.x; a[1] += dit * v0.y; a[2] += dit * v0.z; a[3] += dit * v0.w;
        a[4] += dit * v1.x; a[5] += dit * v1.y; a[6] += dit * v1.z; a[7] += dit * v1.w;
        a[8] += dit * v2.x; a[9] += dit * v2.y; a[10] += dit * v2.z; a[11] += dit * v2.w;
        a[12] += dit * v3.x; a[13] += dit * v3.y; a[14] += dit * v3.z; a[15] += dit * v3.w;
        a[16] += dit * v4.x; a[17] += dit * v4.y; a[18] += dit * v4.z; a[19] += dit * v4.w;
    }

    #pragma unroll
    for (int off = 32; off; off >>= 1) {
        #pragma unroll
        for (int c = 0; c < 20; c++) a[c] += __shfl_down(a[c], off, 64);
    }

    __shared__ float wpart[4][20];
    __shared__ float fin[20];
    if (lane == 0) {
        #pragma unroll
        for (int c = 0; c < 20; c++) wpart[wv][c] = a[c];
    }
    __syncthreads();

    const int node = T_NUM + w;
    if (tid < 20) {
        float s = wpart[0][tid] + wpart[1][tid] + wpart[2][tid] + wpart[3][tid];
        float di = rsqrtf((float)(len + 1));
        float gv = g[(size_t)node * 20 + tid];       // already dinv_w-scaled
        if (tid < 10) {
            float m = fmaf(di, s + gv, b_mean[tid]);
            out_mean[(size_t)node * CLS + tid] = m;
            fin[tid] = m;
        } else {
            int c = tid - 10;
            float l = fmaf(di, s + gv, b_ls[c]);
            out_ls[(size_t)node * CLS + c] = l;
            fin[tid] = l;
        }
    }
    __syncthreads();
    if (tid < 10) {
        float m = fin[tid], l = fin[tid + 10];
        z[(size_t)node * CLS + tid] =
            fmaf(eps[(size_t)node * CLS + tid] * 0.01f, expf(l), m);
    }
}

// ---------------- K5: task-side gather + finalize ----------------
__global__ __launch_bounds__(256) void k_gather_task(
        const int* __restrict__ cnt, const unsigned short* __restrict__ csrW,
        const float* __restrict__ g,
        const float* __restrict__ b_mean, const float* __restrict__ b_ls,
        const float* __restrict__ eps,
        float* __restrict__ out_mean, float* __restrict__ out_ls,
        float* __restrict__ z) {
    __shared__ float gw[W_NUM * 21];
    for (int i = threadIdx.x; i < W_NUM * 20; i += blockDim.x)
        gw[(i / 20) * 21 + (i % 20)] = g[(size_t)T_NUM * 20 + i];   // scaled
    __syncthreads();

    int t = blockIdx.x * blockDim.x + threadIdx.x;
    if (t >= T_NUM) return;

    int len = cnt[t];
    int lim = len < CSR_STRIDE ? len : CSR_STRIDE;
    const unsigned short* lst = csrW + (size_t)t * CSR_STRIDE;
    float am[10], al[10];
    #pragma unroll
    for (int c = 0; c < 10; c++) { am[c] = 0.f; al[c] = 0.f; }

    for (int e = 0; e < lim; e++) {
        const float* gg = &gw[lst[e] * 21];
        #pragma unroll
        for (int c = 0; c < 10; c++) {
            am[c] += gg[c];
            al[c] += gg[10 + c];
        }
    }

    float di = rsqrtf((float)(len + 1));
    union { float4 v[5]; float f[20]; } grow;
    const float4* gr = (const float4*)(g + (size_t)t * 20);
    #pragma unroll
    for (int c = 0; c < 5; c++) grow.v[c] = gr[c];
    #pragma unroll
    for (int k = 0; k < 20; k++) grow.f[k] *= di;    // raw -> dinv_t-scaled

    const float2* ep2 = (const float2*)(eps + (size_t)t * CLS);
    float2* om2 = (float2*)(out_mean + (size_t)t * CLS);
    float2* ol2 = (float2*)(out_ls + (size_t)t * CLS);
    float2* z2  = (float2*)(z + (size_t)t * CLS);
    #pragma unroll
    for (int c = 0; c < 5; c++) {
        float2 ev = ep2[c];
        float m0 = fmaf(di, am[2 * c] + grow.f[2 * c], b_mean[2 * c]);
        float m1 = fmaf(di, am[2 * c + 1] + grow.f[2 * c + 1], b_mean[2 * c + 1]);
        float l0 = fmaf(di, al[2 * c] + grow.f[10 + 2 * c], b_ls[2 * c]);
        float l1 = fmaf(di, al[2 * c + 1] + grow.f[10 + 2 * c + 1], b_ls[2 * c + 1]);
        om2[c] = make_float2(m0, m1);
        ol2[c] = make_float2(l0, l1);
        z2[c]  = make_float2(fmaf(ev.x * 0.01f, expf(l0), m0),
                             fmaf(ev.y * 0.01f, expf(l1), m1));
    }
}

// ---------------- K6: crowd_out (5 threads/answer, coalesced) ----------
__global__ void k_crowd(const int* __restrict__ answers, const float* __restrict__ z,
                        float* __restrict__ out) {
    int i = blockIdx.x * blockDim.x + threadIdx.x;
    if (i >= A_NUM * 5) return;
    int a = i / 5, c2 = i % 5;
    int t = answers[a * 3 + 0];
    int w = answers[a * 3 + 1];
    float2 x = *(const float2*)(z + (size_t)t * CLS + c2 * 2);
    float2 y = *(const float2*)(z + (size_t)(T_NUM + w) * CLS + c2 * 2);
    *(float2*)(out + (size_t)i * 2) = make_float2(x.x * y.x, x.y * y.y);
}

extern "C" void kernel_launch(void* const* d_in, const int* in_sizes, int n_in,
                              void* d_out, int out_size, void* d_ws, size_t ws_size,
                              hipStream_t stream) {
    const float* task_feature   = (const float*)d_in[0];
    const int*   answers        = (const int*)d_in[1];
    const float* worker_feature = (const float*)d_in[2];
    const float* W_efc          = (const float*)d_in[3];
    const float* b_efc          = (const float*)d_in[4];
    const float* W_mean         = (const float*)d_in[5];
    const float* b_mean         = (const float*)d_in[6];
    const float* W_ls           = (const float*)d_in[7];
    const float* b_ls           = (const float*)d_in[8];
    const float* eps            = (const float*)d_in[9];

    float* out       = (float*)d_out;
    float* out_crowd = out;                              // [A, C]
    float* out_mean  = out + (size_t)A_NUM * CLS;        // [N, C]
    float* out_ls    = out_mean + (size_t)N_NODES * CLS; // [N, C]

    // workspace layout
    char* ws = (char*)d_ws;
    int* cnt              = (int*)ws;                         // 402,000 B (+pad)
    int* wcur             = (int*)(ws + 402432);              // 32,000 B
    int* tick             = (int*)(ws + 434432);              // 512 B
    unsigned short* csrW  = (unsigned short*)(ws + 434944);   // 8,000,000 B
    unsigned short* Wt    = (unsigned short*)(ws + 8434944);  // 131,072 B
    unsigned short* B2t   = (unsigned short*)(ws + 8566016);  // 8,192 B
    int* csrT             = (int*)(ws + 8574208);             // 4,864,000 B
    float* g              = (float*)(ws + 13438208);          // 8,040,000 B
    float* z              = (float*)(ws + 21478208);          // 4,020,000 B

    hipMemsetAsync(ws, 0, 434944, stream);

    k_prepw<<<HID + 1, 256, 0, stream>>>(W_efc, Wt, B2t, W_mean, W_ls);
    k_fused<<<GEMM_BLKS + BUILD_BLKS, 256, 0, stream>>>(
        task_feature, Wt, b_efc, B2t, g,
        answers, cnt, wcur, tick, csrW, csrT);
    k_wproj<<<(W_NUM * 20 + 255) / 256, 256, 0, stream>>>(
        worker_feature, W_mean, W_ls, wcur, g);
    k_wacc<<<W_NUM, 256, 0, stream>>>(csrT, wcur, cnt, g, b_mean, b_ls, eps,
                                      out_mean, out_ls, z);
    k_gather_task<<<(T_NUM + 255) / 256, 256, 0, stream>>>(
        cnt, csrW, g, b_mean, b_ls, eps, out_mean, out_ls, z);
    k_crowd<<<(A_NUM * 5 + 255) / 256, 256, 0, stream>>>(answers, z, out_crowd);
}

// Round 15
// 192.783 us; speedup vs baseline: 1.1021x; 1.1021x over previous
//
#include <hip/hip_runtime.h>

#define T_NUM   100000
#define W_NUM   500
#define N_NODES 100500
#define A_NUM   1000000
#define FEAT    512
#define HID     128
#define CLS     10

#define CSR_STRIDE  40       // per-task worker slots; Poisson(10) tail @40 ~ 3e-16
#define CSRT_STRIDE 2432     // per-worker task slots; Binomial(1M,1/500) 9-sigma
#define BM          64       // GEMM rows per block (4 waves x 16 rows)
#define HPAD        136      // Hs row stride (bf16 elems)
#define NRANGE      8        // XCDs
#define TRNG        (T_NUM / NRANGE)   // 12500 tasks per XCD
#define WRNG        64       // workers per XCD range (last: 52)
#define CHUNK       2048
#define NCHUNK      ((A_NUM + CHUNK - 1) / CHUNK)   // 489
#define BLD_CAP     64       // per-(block,worker) LDS slots
#define GT_BLKS     ((T_NUM + 255) / 256)            // 391 gather blocks

typedef short bf16x8 __attribute__((ext_vector_type(8)));
typedef float f32x4  __attribute__((ext_vector_type(4)));

__device__ __forceinline__ unsigned cvtpk(float lo, float hi) {
    unsigned r;
    asm("v_cvt_pk_bf16_f32 %0, %1, %2" : "=v"(r) : "v"(lo), "v"(hi));
    return r;
}
__device__ __forceinline__ unsigned short f2bf1(float x) {
    return (unsigned short)cvtpk(x, x);
}

// ---------------- K1: CSR build — XCD-pinned slices + NT answer stream ----
__global__ __launch_bounds__(256) void k_build(
        const int* __restrict__ answers, int* __restrict__ cnt,
        int* __restrict__ wcur, int* __restrict__ tick,
        unsigned short* __restrict__ csrW, int* __restrict__ csrT) {
    __shared__ int lcnt[WRNG];
    __shared__ int llist[WRNG * BLD_CAP];
    __shared__ int s_chunk;

    int xcc;
    asm volatile("s_getreg_b32 %0, hwreg(HW_REG_XCC_ID)" : "=s"(xcc));
    const int r   = xcc & (NRANGE - 1);
    const int tlo = r * TRNG, thi = tlo + TRNG;
    const int wlo = r * WRNG;

    for (int i = threadIdx.x; i < WRNG; i += 256) lcnt[i] = 0;

    for (;;) {
        __syncthreads();
        if (threadIdx.x == 0) s_chunk = atomicAdd(&tick[r * 16], 1);
        __syncthreads();
        const int c = s_chunk;
        if (c >= NCHUNK) break;
        const int base = c * CHUNK;
        const int end  = (base + CHUNK < A_NUM) ? base + CHUNK : A_NUM;
        for (int a = base + threadIdx.x; a < end; a += 256) {
            int t = __builtin_nontemporal_load(answers + a * 3);
            int w = __builtin_nontemporal_load(answers + a * 3 + 1);
            if (t >= tlo && t < thi) {
                int p = atomicAdd(&cnt[t], 1);
                if (p < CSR_STRIDE) csrW[(size_t)t * CSR_STRIDE + p] = (unsigned short)w;
            }
            int wr = w - wlo;
            if (wr >= 0 && wr < WRNG && w < W_NUM) {
                int s = atomicAdd(&lcnt[wr], 1);
                if (s < BLD_CAP) llist[wr * BLD_CAP + s] = t;
                else {                                   // overflow fallback
                    int q = atomicAdd(&wcur[w * 16], 1);
                    if (q < CSRT_STRIDE) csrT[(size_t)w * CSRT_STRIDE + q] = t;
                }
            }
        }
    }
    __syncthreads();

    for (int wr = threadIdx.x; wr < WRNG; wr += 256) {
        int w = wlo + wr;
        if (w >= W_NUM) continue;
        int c = lcnt[wr];
        if (c > BLD_CAP) c = BLD_CAP;
        if (c == 0) continue;
        int qb = atomicAdd(&wcur[w * 16], c);
        int* dst = csrT + (size_t)w * CSRT_STRIDE;
        for (int j = 0; j < c; j++) {
            int q = qb + j;
            if (q < CSRT_STRIDE) dst[q] = llist[wr * BLD_CAP + j];
        }
    }
}

// ---------------- K2: weight preps + worker projections ----------------
__global__ void k_prepw(const float* __restrict__ W, unsigned short* __restrict__ Wt,
                        unsigned short* __restrict__ B2t,
                        const float* __restrict__ WF,
                        const float* __restrict__ Wm, const float* __restrict__ Wl,
                        const int* __restrict__ wcur,
                        float* __restrict__ g) {
    int bid = blockIdx.x;
    if (bid < HID) {
        int c = bid;
        for (int k = threadIdx.x; k < FEAT; k += blockDim.x)
            Wt[(size_t)c * FEAT + k] = f2bf1(W[(size_t)k * HID + c]);
    } else if (bid == HID) {
        for (int i = threadIdx.x; i < 32 * HID; i += blockDim.x) {
            int c = i / HID, k = i % HID;
            float v = 0.f;
            if (c < 10)                 v = Wm[k * CLS + c];
            else if (c >= 16 && c < 26) v = Wl[k * CLS + (c - 16)];
            B2t[i] = f2bf1(v);
        }
    } else {
        int idx = (bid - HID - 1) * blockDim.x + threadIdx.x;
        if (idx >= W_NUM * 20) return;
        int w = idx / 20, oc = idx % 20;
        const float* Wc = (oc < 10) ? (Wm + oc) : (Wl + (oc - 10));
        const float* x  = WF + (size_t)w * HID;
        float s = 0.f;
        #pragma unroll 8
        for (int k = 0; k < HID; k++) s = fmaf(x[k], Wc[k * CLS], s);
        float gi = rsqrtf((float)(wcur[w * 16] + 1)) * s;
        g[(size_t)(T_NUM + w) * 20 + oc] = gi;
    }
}

// ---------------- K3: MFMA GEMM (scaled-g epilogue; high occupancy) -------
__global__ __launch_bounds__(256, 7) void k_gemm_mfma(
        const float* __restrict__ A, const unsigned short* __restrict__ Wt,
        const float* __restrict__ bias, const unsigned short* __restrict__ B2t,
        const int* __restrict__ cnt, float* __restrict__ g) {
    __shared__ __align__(16) char smem[17408];

    const int tid  = threadIdx.x;
    const int lane = tid & 63;
    const int wv   = tid >> 6;
    const int l15  = lane & 15;
    const int lkg  = lane >> 4;
    const int row  = blockIdx.x * BM + wv * 16 + l15;
    const int rowc = row < T_NUM ? row : T_NUM - 1;
    const float* aptr = A + (size_t)rowc * FEAT + lkg * 8;

    const int scol  = tid >> 1;
    const int shalf = tid & 1;
    const int sswz  = (scol & 7) << 4;
    const int sb0   = (scol * 64 + shalf * 32) ^ sswz;
    const int sb1   = (scol * 64 + shalf * 32 + 16) ^ sswz;
    const unsigned short* sptr = Wt + (size_t)scol * FEAT + shalf * 16;

    const int rswz = (l15 & 7) << 4;

    f32x4 acc[8];
    #pragma unroll
    for (int nt = 0; nt < 8; nt++) acc[nt] = (f32x4){0.f, 0.f, 0.f, 0.f};

    union LU { int4 i; bf16x8 h; };
    union PK { unsigned u[4]; bf16x8 h; };

    float4 ca0 = *(const float4*)(aptr);
    float4 ca1 = *(const float4*)(aptr + 4);
    *(int4*)(smem + sb0) = *(const int4*)(sptr);
    *(int4*)(smem + sb1) = *(const int4*)(sptr + 8);
    __syncthreads();

    for (int ks = 0; ks < 16; ks++) {
        const int k0 = ks * 32;
        float4 na0, na1;
        if (ks < 15) {
            na0 = *(const float4*)(aptr + k0 + 32);
            na1 = *(const float4*)(aptr + k0 + 36);
            char* nb = smem + (((ks + 1) & 1) << 13);
            *(int4*)(nb + sb0) = *(const int4*)(sptr + k0 + 32);
            *(int4*)(nb + sb1) = *(const int4*)(sptr + k0 + 40);
        }
        PK pk;
        pk.u[0] = cvtpk(ca0.x, ca0.y);
        pk.u[1] = cvtpk(ca0.z, ca0.w);
        pk.u[2] = cvtpk(ca1.x, ca1.y);
        pk.u[3] = cvtpk(ca1.z, ca1.w);
        const char* bb = smem + ((ks & 1) << 13);
        #pragma unroll
        for (int nt = 0; nt < 8; nt++) {
            const int boff = ((nt * 16 + l15) * 64 + lkg * 16) ^ rswz;
            LU bu; bu.i = *(const int4*)(bb + boff);
            acc[nt] = __builtin_amdgcn_mfma_f32_16x16x32_bf16(pk.h, bu.h, acc[nt], 0, 0, 0);
        }
        ca0 = na0; ca1 = na1;
        __syncthreads();
    }

    unsigned short* hw = (unsigned short*)smem + wv * 16 * HPAD;
    #pragma unroll
    for (int nt = 0; nt < 8; nt++) {
        float bv = bias[nt * 16 + l15];
        #pragma unroll
        for (int r = 0; r < 4; r++) {
            float h = fmaxf(acc[nt][r] + bv, 0.f);
            hw[(lkg * 4 + r) * HPAD + nt * 16 + l15] = f2bf1(h);
        }
    }

    f32x4 acc2[2];
    acc2[0] = (f32x4){0.f, 0.f, 0.f, 0.f};
    acc2[1] = (f32x4){0.f, 0.f, 0.f, 0.f};
    #pragma unroll
    for (int s = 0; s < 4; s++) {
        LU a2;
        a2.i = *(const int4*)(hw + l15 * HPAD + s * 32 + lkg * 8);
        #pragma unroll
        for (int j = 0; j < 2; j++) {
            LU b2;
            b2.i = *(const int4*)(B2t + (size_t)(j * 16 + l15) * HID + s * 32 + lkg * 8);
            acc2[j] = __builtin_amdgcn_mfma_f32_16x16x32_bf16(a2.h, b2.h, acc2[j], 0, 0, 0);
        }
    }

    if (l15 < 10) {
        #pragma unroll
        for (int r = 0; r < 4; r++) {
            int node = blockIdx.x * BM + wv * 16 + lkg * 4 + r;
            if (node < T_NUM) {
                float di = rsqrtf((float)(cnt[node] + 1));
                g[(size_t)node * 20 + l15]      = di * acc2[0][r];
                g[(size_t)node * 20 + 10 + l15] = di * acc2[1][r];
            }
        }
    }
}

// ---------------- K4: FUSED finalize (gather-task blocks | wacc blocks) ---
// blocks [0,GT_BLKS): task-side gather+finalize; blocks [GT_BLKS,GT_BLKS+500):
// worker accumulation+finalize. Independent given build+prepw+gemm done;
// wacc's ~10us hides under gather's tail. Shared 42KB LDS region.
__global__ __launch_bounds__(256) void k_final(
        const int* __restrict__ cnt, const unsigned short* __restrict__ csrW,
        const int* __restrict__ csrT, const int* __restrict__ wcur,
        const float* __restrict__ g,
        const float* __restrict__ b_mean, const float* __restrict__ b_ls,
        const float* __restrict__ eps,
        float* __restrict__ out_mean, float* __restrict__ out_ls,
        float* __restrict__ z) {
    __shared__ float smem[W_NUM * 21];
    const int tid = threadIdx.x;

    if (blockIdx.x >= GT_BLKS) {
        // ================= wacc path =================
        const int w    = blockIdx.x - GT_BLKS;
        const int lane = tid & 63;
        const int wv   = tid >> 6;

        int len = wcur[w * 16];
        int lim = len < CSRT_STRIDE ? len : CSRT_STRIDE;
        const int* lst = csrT + (size_t)w * CSRT_STRIDE;

        float a[20];
        #pragma unroll
        for (int c = 0; c < 20; c++) a[c] = 0.f;

        for (int e = tid; e < lim; e += 256) {
            int t = lst[e];
            const float4* gr = (const float4*)(g + (size_t)t * 20);
            float4 v0 = gr[0], v1 = gr[1], v2 = gr[2], v3 = gr[3], v4 = gr[4];
            a[0] += v0.x; a[1] += v0.y; a[2] += v0.z; a[3] += v0.w;
            a[4] += v1.x; a[5] += v1.y; a[6] += v1.z; a[7] += v1.w;
            a[8] += v2.x; a[9] += v2.y; a[10] += v2.z; a[11] += v2.w;
            a[12] += v3.x; a[13] += v3.y; a[14] += v3.z; a[15] += v3.w;
            a[16] += v4.x; a[17] += v4.y; a[18] += v4.z; a[19] += v4.w;
        }

        #pragma unroll
        for (int off = 32; off; off >>= 1) {
            #pragma unroll
            for (int c = 0; c < 20; c++) a[c] += __shfl_down(a[c], off, 64);
        }

        float* wpart = smem;            // [4][20]
        float* fin   = smem + 80;       // [20]
        if (lane == 0) {
            #pragma unroll
            for (int c = 0; c < 20; c++) wpart[wv * 20 + c] = a[c];
        }
        __syncthreads();

        const int node = T_NUM + w;
        if (tid < 20) {
            float s = wpart[tid] + wpart[20 + tid] + wpart[40 + tid] + wpart[60 + tid];
            float di = rsqrtf((float)(len + 1));
            float gv = g[(size_t)node * 20 + tid];
            if (tid < 10) {
                float m = fmaf(di, s + gv, b_mean[tid]);
                out_mean[(size_t)node * CLS + tid] = m;
                fin[tid] = m;
            } else {
                int c = tid - 10;
                float l = fmaf(di, s + gv, b_ls[c]);
                out_ls[(size_t)node * CLS + c] = l;
                fin[tid] = l;
            }
        }
        __syncthreads();
        if (tid < 10) {
            float m = fin[tid], l = fin[tid + 10];
            z[(size_t)node * CLS + tid] =
                fmaf(eps[(size_t)node * CLS + tid] * 0.01f, expf(l), m);
        }
        return;
    }

    // ================= gather-task path =================
    float* gw = smem;
    for (int i = tid; i < W_NUM * 20; i += 256)
        gw[(i / 20) * 21 + (i % 20)] = g[(size_t)T_NUM * 20 + i];
    __syncthreads();

    int t = blockIdx.x * 256 + tid;
    if (t >= T_NUM) return;

    int len = cnt[t];
    int lim = len < CSR_STRIDE ? len : CSR_STRIDE;
    const unsigned short* lst = csrW + (size_t)t * CSR_STRIDE;
    float am[10], al[10];
    #pragma unroll
    for (int c = 0; c < 10; c++) { am[c] = 0.f; al[c] = 0.f; }

    for (int e = 0; e < lim; e++) {
        const float* gg = &gw[lst[e] * 21];
        #pragma unroll
        for (int c = 0; c < 10; c++) {
            am[c] += gg[c];
            al[c] += gg[10 + c];
        }
    }

    float di = rsqrtf((float)(len + 1));
    union { float4 v[5]; float f[20]; } grow;
    const float4* gr = (const float4*)(g + (size_t)t * 20);
    #pragma unroll
    for (int c = 0; c < 5; c++) grow.v[c] = gr[c];

    const float2* ep2 = (const float2*)(eps + (size_t)t * CLS);
    float2* om2 = (float2*)(out_mean + (size_t)t * CLS);
    float2* ol2 = (float2*)(out_ls + (size_t)t * CLS);
    float2* z2  = (float2*)(z + (size_t)t * CLS);
    #pragma unroll
    for (int c = 0; c < 5; c++) {
        float2 ev = ep2[c];
        float m0 = fmaf(di, am[2 * c] + grow.f[2 * c], b_mean[2 * c]);
        float m1 = fmaf(di, am[2 * c + 1] + grow.f[2 * c + 1], b_mean[2 * c + 1]);
        float l0 = fmaf(di, al[2 * c] + grow.f[10 + 2 * c], b_ls[2 * c]);
        float l1 = fmaf(di, al[2 * c + 1] + grow.f[10 + 2 * c + 1], b_ls[2 * c + 1]);
        om2[c] = make_float2(m0, m1);
        ol2[c] = make_float2(l0, l1);
        z2[c]  = make_float2(fmaf(ev.x * 0.01f, expf(l0), m0),
                             fmaf(ev.y * 0.01f, expf(l1), m1));
    }
}

// ---------------- K5: crowd_out (5 thr/answer; NT in/out; z cached) -------
__global__ void k_crowd(const int* __restrict__ answers, const float* __restrict__ z,
                        float* __restrict__ out) {
    int i = blockIdx.x * blockDim.x + threadIdx.x;
    if (i >= A_NUM * 5) return;
    int a = i / 5, c2 = i % 5;
    int t = __builtin_nontemporal_load(answers + a * 3);
    int w = __builtin_nontemporal_load(answers + a * 3 + 1);
    float2 x = *(const float2*)(z + (size_t)t * CLS + c2 * 2);
    float2 y = *(const float2*)(z + (size_t)(T_NUM + w) * CLS + c2 * 2);
    float2 o = make_float2(x.x * y.x, x.y * y.y);
    __builtin_nontemporal_store(o.x, out + (size_t)i * 2);
    __builtin_nontemporal_store(o.y, out + (size_t)i * 2 + 1);
}

extern "C" void kernel_launch(void* const* d_in, const int* in_sizes, int n_in,
                              void* d_out, int out_size, void* d_ws, size_t ws_size,
                              hipStream_t stream) {
    const float* task_feature   = (const float*)d_in[0];
    const int*   answers        = (const int*)d_in[1];
    const float* worker_feature = (const float*)d_in[2];
    const float* W_efc          = (const float*)d_in[3];
    const float* b_efc          = (const float*)d_in[4];
    const float* W_mean         = (const float*)d_in[5];
    const float* b_mean         = (const float*)d_in[6];
    const float* W_ls           = (const float*)d_in[7];
    const float* b_ls           = (const float*)d_in[8];
    const float* eps            = (const float*)d_in[9];

    float* out       = (float*)d_out;
    float* out_crowd = out;                              // [A, C]
    float* out_mean  = out + (size_t)A_NUM * CLS;        // [N, C]
    float* out_ls    = out_mean + (size_t)N_NODES * CLS; // [N, C]

    // workspace layout
    char* ws = (char*)d_ws;
    int* cnt              = (int*)ws;                         // 402,000 B (+pad)
    int* wcur             = (int*)(ws + 402432);              // 32,000 B
    int* tick             = (int*)(ws + 434432);              // 512 B
    unsigned short* csrW  = (unsigned short*)(ws + 434944);   // 8,000,000 B
    unsigned short* Wt    = (unsigned short*)(ws + 8434944);  // 131,072 B
    unsigned short* B2t   = (unsigned short*)(ws + 8566016);  // 8,192 B
    int* csrT             = (int*)(ws + 8574208);             // 4,864,000 B
    float* g              = (float*)(ws + 13438208);          // 8,040,000 B
    float* z              = (float*)(ws + 21478208);          // 4,020,000 B

    hipMemsetAsync(ws, 0, 434944, stream);

    k_build<<<2048, 256, 0, stream>>>(answers, cnt, wcur, tick, csrW, csrT);
    k_prepw<<<HID + 1 + (W_NUM * 20 + 255) / 256, 256, 0, stream>>>(
        W_efc, Wt, B2t, worker_feature, W_mean, W_ls, wcur, g);
    k_gemm_mfma<<<(T_NUM + BM - 1) / BM, 256, 0, stream>>>(
        task_feature, Wt, b_efc, B2t, cnt, g);
    k_final<<<GT_BLKS + W_NUM, 256, 0, stream>>>(
        cnt, csrW, csrT, wcur, g, b_mean, b_ls, eps, out_mean, out_ls, z);
    k_crowd<<<(A_NUM * 5 + 255) / 256, 256, 0, stream>>>(answers, z, out_crowd);
}